// Round 12
// baseline (80.286 us; speedup 1.0000x reference)
//
#include <hip/hip_runtime.h>
#include <hip/hip_bf16.h>

// Problem constants (DistanceProbe): B=8, S=512, D=1024, R=128
constexpr int B_ = 8;
constexpr int S_ = 512;
constexpr int D_ = 1024;
constexpr int R_ = 128;
constexpr int M_ = B_ * S_;   // 4096 rows of T

typedef unsigned short u16;
typedef __attribute__((ext_vector_type(8))) short short8;  // 8 bf16 (4 VGPRs) MFMA A/B frag
typedef __attribute__((ext_vector_type(4))) float f32x4;   // MFMA C/D frag

// fp32 -> bf16 round-to-nearest-even
static __device__ __forceinline__ u16 f2bf(float f) {
    unsigned u = __float_as_uint(f);
    u += 0x7fffu + ((u >> 16) & 1u);
    return (u16)(u >> 16);
}
static __device__ __forceinline__ float bf2f(u16 u) {
    return __uint_as_float((unsigned)u << 16);
}

// ---------------------------------------------------------------------------
// Kernel 1: proj [1024][128] fp32 -> Pt [16 ktiles][128 cols][64 k] bf16.
// Grid (16,4): blockIdx.x = 64-k tile, blockIdx.y = 16-k subtile.
// ---------------------------------------------------------------------------
__global__ __launch_bounds__(256) void transpose_proj_kernel(
    const float* __restrict__ P, u16* __restrict__ Pt)
{
    __shared__ float S[16][132];
    const int t  = threadIdx.x;
    const int kk = blockIdx.x;
    const int kq = blockIdx.y;

#pragma unroll
    for (int p = 0; p < 2; ++p) {
        const int k = (t >> 5) + p * 8;       // 0..15
        const int c = (t & 31) * 4;           // 0..124
        *reinterpret_cast<float4*>(&S[k][c]) =
            *reinterpret_cast<const float4*>(
                &P[(size_t)(kk * 64 + kq * 16 + k) * R_ + c]);
    }
    __syncthreads();

    const int col = t >> 1;     // 0..127
    const int h   = t & 1;      // k-octet within the 16-k subtile
    unsigned u[4];
#pragma unroll
    for (int q = 0; q < 4; ++q) {
        const u16 lo = f2bf(S[h * 8 + q * 2 + 0][col]);
        const u16 hi = f2bf(S[h * 8 + q * 2 + 1][col]);
        u[q] = (unsigned)lo | ((unsigned)hi << 16);
    }
    *reinterpret_cast<uint4*>(&Pt[(size_t)kk * 8192 + col * 64 + kq * 16 + h * 8]) =
        make_uint4(u[0], u[1], u[2], u[3]);
}

// ---------------------------------------------------------------------------
// Kernel 2: T[4096][128] bf16 = batch @ proj via bf16 MFMA.
// Grid 256 blocks (1/CU), 256 thr = 4 waves. Block: 16 rows x 128 cols.
// Wave w owns cols w*32..+31 (2 n-frags).
//
// Anti-barrier-drain structure (m97: compiler emits vmcnt(0) before every
// s_barrier, so cross-barrier register prefetch is drained each iteration):
//  * ALL 16 A-tiles preloaded into VGPRs up front (16 x float4 per thread,
//    statically indexed) -> ONE bulk drain at the first barrier, BW-bound.
//  * B (Pt, 256 KB, L2-resident) prefetched one tile ahead into regs;
//    its per-iter drain costs only ~L2 latency.
//  * Double-buffered LDS -> single barrier per K-iter: at barrier(kk) the
//    compiler's lgkmcnt(0) drains iter-(kk-1) ds ops, and buf[(kk-1)&1]
//    is only rewritten in iter kk+1 (strictly after barrier(kk)) -> safe.
//
// STAGING COVERAGE (audit, round-9 bug): Bs tile = 128 cols x 64 k x 2 B
// = 16 KB = 256 thr x 64 B  ->  each thread MUST write 4 uint4 (bp0..bp3).
// As tile = 16 x 64 x 2 B = 2 KB = 256 thr x uint2. Both exact.
//
// A/B frags share k-map kappa(g,e)=g*8+e (consistent => correct under any
// HW k-permutation). C/D layout (m89): col=l&15, row=(l>>4)*4+reg.
// ---------------------------------------------------------------------------
__global__ __launch_bounds__(256) void gemm1_kernel(
    const float* __restrict__ A,    // batch [4096][1024] fp32
    const u16* __restrict__ Pt,     // [16][128][64] bf16 (proj^T tiled)
    u16* __restrict__ T)            // [4096][128] bf16
{
    __shared__ u16 As[2][16][72];   // [buf][row][k]
    __shared__ u16 Bs[2][128][72];  // [buf][col][k]

    const int t    = threadIdx.x;
    const int row0 = blockIdx.x * 16;
    const int w    = t >> 6;        // wave 0..3 -> cols w*32..+31
    const int l    = t & 63;
    const int g    = l >> 4;        // 0..3
    const int l15  = l & 15;

    f32x4 acc[2];
    acc[0] = f32x4{0.f, 0.f, 0.f, 0.f};
    acc[1] = f32x4{0.f, 0.f, 0.f, 0.f};

    // staging maps
    const int ar = t >> 4;          // A row 0..15
    const int aq = t & 15;          // A k sub-lane (float4 -> k = aq*4)
    const int bcol = t >> 1;        // B col 0..127
    const int bh   = t & 1;         // B k-half -> k = bh*32 (32 bf16 = 64 B)

    const float* Abase = &A[(size_t)(row0 + ar) * D_ + aq * 4];

    // ---- preload ALL A tiles into registers (static indices only)
    float4 areg[16];
#pragma unroll
    for (int kk = 0; kk < 16; ++kk)
        areg[kk] = *reinterpret_cast<const float4*>(Abase + kk * 64);

    // ---- preload B tile 0 (64 B per thread = 4 uint4)
    const uint4* b0src = reinterpret_cast<const uint4*>(
        &Pt[(size_t)0 * 8192 + bcol * 64 + bh * 32]);
    uint4 bp0 = b0src[0];
    uint4 bp1 = b0src[1];
    uint4 bp2 = b0src[2];
    uint4 bp3 = b0src[3];

#pragma unroll
    for (int kk = 0; kk < 16; ++kk) {
        const int cur = kk & 1;
        // write current tile to LDS (consumes areg[kk], bp0..bp3)
        {
            const float4 v = areg[kk];
            const u16 c0 = f2bf(v.x), c1 = f2bf(v.y), c2 = f2bf(v.z), c3 = f2bf(v.w);
            const unsigned lo = (unsigned)c0 | ((unsigned)c1 << 16);
            const unsigned hi = (unsigned)c2 | ((unsigned)c3 << 16);
            *reinterpret_cast<uint2*>(&As[cur][ar][aq * 4]) = make_uint2(lo, hi);
            uint4* bdst = reinterpret_cast<uint4*>(&Bs[cur][bcol][bh * 32]);
            bdst[0] = bp0;
            bdst[1] = bp1;
            bdst[2] = bp2;
            bdst[3] = bp3;
        }
        // prefetch next B tile (uniform branch; L2-resident)
        if (kk + 1 < 16) {
            const uint4* bs = reinterpret_cast<const uint4*>(
                &Pt[(size_t)(kk + 1) * 8192 + bcol * 64 + bh * 32]);
            bp0 = bs[0];
            bp1 = bs[1];
            bp2 = bs[2];
            bp3 = bs[3];
        }
        __syncthreads();

        // MFMA: 2 k-steps x 2 n-frags
#pragma unroll
        for (int h2 = 0; h2 < 2; ++h2) {
            const short8 a = *reinterpret_cast<const short8*>(
                &As[cur][l15][h2 * 32 + g * 8]);
#pragma unroll
            for (int n = 0; n < 2; ++n) {
                const short8 b = *reinterpret_cast<const short8*>(
                    &Bs[cur][w * 32 + n * 16 + l15][h2 * 32 + g * 8]);
                acc[n] = __builtin_amdgcn_mfma_f32_16x16x32_bf16(a, b, acc[n], 0, 0, 0);
            }
        }
        // no second barrier: next iter writes the other buffer; the barrier
        // above (with compiler lgkmcnt(0) drain) protects buffer reuse.
    }

    // epilogue: C/D layout col=l15, row=g*4+reg
#pragma unroll
    for (int n = 0; n < 2; ++n) {
#pragma unroll
        for (int r = 0; r < 4; ++r) {
            const int row = row0 + g * 4 + r;
            const int col = w * 32 + n * 16 + l15;
            T[(size_t)row * R_ + col] = f2bf(acc[n][r]);
        }
    }
}

// ---------------------------------------------------------------------------
// Kernel 3: out[b][i][j] = ni + nj - 2 * (T_i . T_j)   via bf16 MFMA.
// Grid (8,8,8) = 512 blocks; 256 thr = 4 waves; 64x64 tile; K=128 one stage.
// ---------------------------------------------------------------------------
__global__ __launch_bounds__(256) void pairdist_kernel(
    const u16* __restrict__ T,      // [8*512][128] bf16
    float* __restrict__ out)        // [8][512][512] fp32
{
    __shared__ u16 Ti[64][136];
    __shared__ u16 Tj[64][136];
    __shared__ float ni[64], nj[64];

    const int t  = threadIdx.x;
    const int b  = blockIdx.z;
    const int i0 = blockIdx.y * 64;
    const int j0 = blockIdx.x * 64;
    const u16* Tb = T + (size_t)b * S_ * R_;

    const int w   = t >> 6;
    const int l   = t & 63;
    const int g   = l >> 4;
    const int l15 = l & 15;

    // stage both 64x128 bf16 panels (each: 64x128x2B = 16 KB = 256 thr x 4 uint4)
    {
        const int r  = t >> 2;          // 0..63
        const int kq = (t & 3) * 32;    // 0,32,64,96
        const uint4* si = reinterpret_cast<const uint4*>(&Tb[(size_t)(i0 + r) * R_ + kq]);
        const uint4* sj = reinterpret_cast<const uint4*>(&Tb[(size_t)(j0 + r) * R_ + kq]);
        uint4* di = reinterpret_cast<uint4*>(&Ti[r][kq]);
        uint4* dj = reinterpret_cast<uint4*>(&Tj[r][kq]);
#pragma unroll
        for (int p = 0; p < 4; ++p) { di[p] = si[p]; dj[p] = sj[p]; }
    }
    __syncthreads();

    // row norms
    if (t < 128) {
        const u16* rowp = (t < 64) ? &Ti[t][0] : &Tj[t - 64][0];
        float s = 0.f;
#pragma unroll
        for (int p = 0; p < 16; ++p) {
            const uint4 v = *reinterpret_cast<const uint4*>(rowp + p * 8);
            const unsigned uu[4] = {v.x, v.y, v.z, v.w};
#pragma unroll
            for (int q = 0; q < 4; ++q) {
                const float f0 = bf2f((u16)(uu[q] & 0xffffu));
                const float f1 = bf2f((u16)(uu[q] >> 16));
                s += f0 * f0 + f1 * f1;
            }
        }
        if (t < 64) ni[t] = s; else nj[t - 64] = s;
    }
    __syncthreads();

    // Gram via MFMA
    f32x4 acc[4];
#pragma unroll
    for (int n = 0; n < 4; ++n) acc[n] = f32x4{0.f, 0.f, 0.f, 0.f};

#pragma unroll
    for (int kk = 0; kk < 4; ++kk) {
        const short8 a = *reinterpret_cast<const short8*>(
            &Ti[w * 16 + l15][kk * 32 + g * 8]);
#pragma unroll
        for (int n = 0; n < 4; ++n) {
            const short8 bb = *reinterpret_cast<const short8*>(
                &Tj[n * 16 + l15][kk * 32 + g * 8]);
            acc[n] = __builtin_amdgcn_mfma_f32_16x16x32_bf16(a, bb, acc[n], 0, 0, 0);
        }
    }

    // epilogue: out = ni[i] + nj[j] - 2*G
    float niv[4];
#pragma unroll
    for (int r = 0; r < 4; ++r) niv[r] = ni[w * 16 + g * 4 + r];
#pragma unroll
    for (int n = 0; n < 4; ++n) {
        const float njv = nj[n * 16 + l15];
#pragma unroll
        for (int r = 0; r < 4; ++r) {
            const int row = i0 + w * 16 + g * 4 + r;
            const int col = j0 + n * 16 + l15;
            out[((size_t)b * S_ + row) * S_ + col] = niv[r] + njv - 2.f * acc[n][r];
        }
    }
}

// ---------------------------------------------------------------------------
extern "C" void kernel_launch(void* const* d_in, const int* in_sizes, int n_in,
                              void* d_out, int out_size, void* d_ws, size_t ws_size,
                              hipStream_t stream) {
    const float* batch = (const float*)d_in[0];   // [8,512,1024] fp32
    const float* proj  = (const float*)d_in[1];   // [1024,128]  fp32
    float* out = (float*)d_out;                   // [8,512,512] fp32

    // ws layout: Pt bf16 [16][128][64] = 256 KB, then T bf16 [4096][128] = 1 MB
    u16* Pt = (u16*)d_ws;
    u16* T  = Pt + 16 * 8192;

    transpose_proj_kernel<<<dim3(16, 4), 256, 0, stream>>>(proj, Pt);
    gemm1_kernel<<<M_ / 16, 256, 0, stream>>>(batch, Pt, T);
    pairdist_kernel<<<dim3(S_ / 64, S_ / 64, B_), 256, 0, stream>>>(T, out);
}

// Round 13
// 78.732 us; speedup vs baseline: 1.0197x; 1.0197x over previous
//
#include <hip/hip_runtime.h>
#include <hip/hip_bf16.h>

// Problem constants (DistanceProbe): B=8, S=512, D=1024, R=128
constexpr int B_ = 8;
constexpr int S_ = 512;
constexpr int D_ = 1024;
constexpr int R_ = 128;
constexpr int M_ = B_ * S_;   // 4096 rows of T

typedef unsigned short u16;
typedef __attribute__((ext_vector_type(8))) short short8;  // 8 bf16 (4 VGPRs) MFMA A/B frag
typedef __attribute__((ext_vector_type(4))) float f32x4;   // MFMA C/D frag

// fp32 -> bf16 round-to-nearest-even
static __device__ __forceinline__ u16 f2bf(float f) {
    unsigned u = __float_as_uint(f);
    u += 0x7fffu + ((u >> 16) & 1u);
    return (u16)(u >> 16);
}
static __device__ __forceinline__ float bf2f(u16 u) {
    return __uint_as_float((unsigned)u << 16);
}

// ---------------------------------------------------------------------------
// Kernel 1: proj [1024][128] fp32 -> Pt [16 ktiles][128 cols][64 k] bf16.
// Grid (16,4): blockIdx.x = 64-k tile, blockIdx.y = 16-k subtile.
// ---------------------------------------------------------------------------
__global__ __launch_bounds__(256) void transpose_proj_kernel(
    const float* __restrict__ P, u16* __restrict__ Pt)
{
    __shared__ float S[16][132];
    const int t  = threadIdx.x;
    const int kk = blockIdx.x;
    const int kq = blockIdx.y;

#pragma unroll
    for (int p = 0; p < 2; ++p) {
        const int k = (t >> 5) + p * 8;       // 0..15
        const int c = (t & 31) * 4;           // 0..124
        *reinterpret_cast<float4*>(&S[k][c]) =
            *reinterpret_cast<const float4*>(
                &P[(size_t)(kk * 64 + kq * 16 + k) * R_ + c]);
    }
    __syncthreads();

    const int col = t >> 1;     // 0..127
    const int h   = t & 1;      // k-octet within the 16-k subtile
    unsigned u[4];
#pragma unroll
    for (int q = 0; q < 4; ++q) {
        const u16 lo = f2bf(S[h * 8 + q * 2 + 0][col]);
        const u16 hi = f2bf(S[h * 8 + q * 2 + 1][col]);
        u[q] = (unsigned)lo | ((unsigned)hi << 16);
    }
    *reinterpret_cast<uint4*>(&Pt[(size_t)kk * 8192 + col * 64 + kq * 16 + h * 8]) =
        make_uint4(u[0], u[1], u[2], u[3]);
}

// ---------------------------------------------------------------------------
// Kernel 2: T[4096][128] bf16 = batch @ proj via bf16 MFMA.
// Grid (2, 256) = 512 blocks (2/CU -> 2 waves/SIMD TLP). Block: 16 rows x
// 64 cols; wave w owns cols col0 + w*16..+15 (ONE 16x16 frag, K-accumulated).
//
// Anti-barrier-drain structure (m97: compiler emits vmcnt(0) before every
// s_barrier, so cross-barrier register prefetch is drained each iteration):
//  * ALL 16 A-tiles preloaded into VGPRs up front (16 x float4 per thread,
//    statically indexed) -> ONE bulk drain at the first barrier, BW-bound.
//  * B (Pt, 256 KB, L2-resident) prefetched one tile ahead into regs;
//    its per-iter drain costs only ~L2 latency (hidden by 2-block TLP).
//  * Double-buffered LDS -> single barrier per K-iter: at barrier(kk) the
//    compiler's lgkmcnt(0) drains iter-(kk-1) ds ops, and buf[(kk-1)&1]
//    is only rewritten in iter kk+1 (strictly after barrier(kk)) -> safe.
//
// STAGING COVERAGE (audited): As tile = 16r x 64k x 2B = 2 KB = 256 thr x
// uint2 (ar=t>>4, aq=t&15) exact. Bs tile = 64c x 64k x 2B = 8 KB = 256 thr
// x 32 B = 2 uint4 (bcol=t>>2 in 0..63, bq=t&3 -> k=bq*16..+15), disjoint,
// exact. Prefetch reads mirror the writes (2 uint4).
//
// A/B frags share k-map kappa(g,e)=g*8+e (consistent => correct under any
// HW k-permutation). C/D layout (m89): col=l&15, row=(l>>4)*4+reg.
// LDS rows padded to 72 bf16 (144 B) -> b128 frag reads 2-way max (free).
// ---------------------------------------------------------------------------
__global__ __launch_bounds__(256) void gemm1_kernel(
    const float* __restrict__ A,    // batch [4096][1024] fp32
    const u16* __restrict__ Pt,     // [16][128][64] bf16 (proj^T tiled)
    u16* __restrict__ T)            // [4096][128] bf16
{
    __shared__ u16 As[2][16][72];   // [buf][row][k]
    __shared__ u16 Bs[2][64][72];   // [buf][col-local][k]

    const int t    = threadIdx.x;
    const int row0 = blockIdx.y * 16;
    const int col0 = blockIdx.x * 64;   // 0 or 64
    const int w    = t >> 6;        // wave 0..3 -> col frag at col0 + w*16
    const int l    = t & 63;
    const int g    = l >> 4;        // 0..3
    const int l15  = l & 15;

    f32x4 acc = f32x4{0.f, 0.f, 0.f, 0.f};

    // staging maps
    const int ar = t >> 4;          // A row 0..15
    const int aq = t & 15;          // A k sub-lane (float4 -> k = aq*4)
    const int bcol = t >> 2;        // B col-local 0..63
    const int bq   = t & 3;         // B k-quarter -> k = bq*16 (32 B)

    const float* Abase = &A[(size_t)(row0 + ar) * D_ + aq * 4];

    // ---- preload ALL A tiles into registers (static indices only)
    float4 areg[16];
#pragma unroll
    for (int kk = 0; kk < 16; ++kk)
        areg[kk] = *reinterpret_cast<const float4*>(Abase + kk * 64);

    // ---- preload B tile 0 (32 B per thread = 2 uint4)
    const uint4* b0src = reinterpret_cast<const uint4*>(
        &Pt[(size_t)0 * 8192 + (col0 + bcol) * 64 + bq * 16]);
    uint4 bp0 = b0src[0];
    uint4 bp1 = b0src[1];

#pragma unroll
    for (int kk = 0; kk < 16; ++kk) {
        const int cur = kk & 1;
        // write current tile to LDS (consumes areg[kk], bp0/bp1)
        {
            const float4 v = areg[kk];
            const u16 c0 = f2bf(v.x), c1 = f2bf(v.y), c2 = f2bf(v.z), c3 = f2bf(v.w);
            const unsigned lo = (unsigned)c0 | ((unsigned)c1 << 16);
            const unsigned hi = (unsigned)c2 | ((unsigned)c3 << 16);
            *reinterpret_cast<uint2*>(&As[cur][ar][aq * 4]) = make_uint2(lo, hi);
            uint4* bdst = reinterpret_cast<uint4*>(&Bs[cur][bcol][bq * 16]);
            bdst[0] = bp0;
            bdst[1] = bp1;
        }
        // prefetch next B tile (uniform branch; L2-resident)
        if (kk + 1 < 16) {
            const uint4* bs = reinterpret_cast<const uint4*>(
                &Pt[(size_t)(kk + 1) * 8192 + (col0 + bcol) * 64 + bq * 16]);
            bp0 = bs[0];
            bp1 = bs[1];
        }
        __syncthreads();

        // MFMA: 2 k-steps, 1 n-frag per wave
#pragma unroll
        for (int h2 = 0; h2 < 2; ++h2) {
            const short8 a = *reinterpret_cast<const short8*>(
                &As[cur][l15][h2 * 32 + g * 8]);
            const short8 b = *reinterpret_cast<const short8*>(
                &Bs[cur][w * 16 + l15][h2 * 32 + g * 8]);
            acc = __builtin_amdgcn_mfma_f32_16x16x32_bf16(a, b, acc, 0, 0, 0);
        }
        // no second barrier: next iter writes the other buffer; the barrier
        // above (with compiler lgkmcnt(0) drain) protects buffer reuse.
    }

    // epilogue: C/D layout col=l15, row=g*4+reg
#pragma unroll
    for (int r = 0; r < 4; ++r) {
        const int row = row0 + g * 4 + r;
        const int col = col0 + w * 16 + l15;
        T[(size_t)row * R_ + col] = f2bf(acc[r]);
    }
}

// ---------------------------------------------------------------------------
// Kernel 3: out[b][i][j] = ni + nj - 2 * (T_i . T_j)   via bf16 MFMA.
// Grid (8,8,8) = 512 blocks; 256 thr = 4 waves; 64x64 tile; K=128 one stage.
// (unchanged from round 12 -- verified passing)
// ---------------------------------------------------------------------------
__global__ __launch_bounds__(256) void pairdist_kernel(
    const u16* __restrict__ T,      // [8*512][128] bf16
    float* __restrict__ out)        // [8][512][512] fp32
{
    __shared__ u16 Ti[64][136];
    __shared__ u16 Tj[64][136];
    __shared__ float ni[64], nj[64];

    const int t  = threadIdx.x;
    const int b  = blockIdx.z;
    const int i0 = blockIdx.y * 64;
    const int j0 = blockIdx.x * 64;
    const u16* Tb = T + (size_t)b * S_ * R_;

    const int w   = t >> 6;
    const int l   = t & 63;
    const int g   = l >> 4;
    const int l15 = l & 15;

    // stage both 64x128 bf16 panels (each: 16 KB = 256 thr x 4 uint4)
    {
        const int r  = t >> 2;          // 0..63
        const int kq = (t & 3) * 32;    // 0,32,64,96
        const uint4* si = reinterpret_cast<const uint4*>(&Tb[(size_t)(i0 + r) * R_ + kq]);
        const uint4* sj = reinterpret_cast<const uint4*>(&Tb[(size_t)(j0 + r) * R_ + kq]);
        uint4* di = reinterpret_cast<uint4*>(&Ti[r][kq]);
        uint4* dj = reinterpret_cast<uint4*>(&Tj[r][kq]);
#pragma unroll
        for (int p = 0; p < 4; ++p) { di[p] = si[p]; dj[p] = sj[p]; }
    }
    __syncthreads();

    // row norms
    if (t < 128) {
        const u16* rowp = (t < 64) ? &Ti[t][0] : &Tj[t - 64][0];
        float s = 0.f;
#pragma unroll
        for (int p = 0; p < 16; ++p) {
            const uint4 v = *reinterpret_cast<const uint4*>(rowp + p * 8);
            const unsigned uu[4] = {v.x, v.y, v.z, v.w};
#pragma unroll
            for (int q = 0; q < 4; ++q) {
                const float f0 = bf2f((u16)(uu[q] & 0xffffu));
                const float f1 = bf2f((u16)(uu[q] >> 16));
                s += f0 * f0 + f1 * f1;
            }
        }
        if (t < 64) ni[t] = s; else nj[t - 64] = s;
    }
    __syncthreads();

    // Gram via MFMA
    f32x4 acc[4];
#pragma unroll
    for (int n = 0; n < 4; ++n) acc[n] = f32x4{0.f, 0.f, 0.f, 0.f};

#pragma unroll
    for (int kk = 0; kk < 4; ++kk) {
        const short8 a = *reinterpret_cast<const short8*>(
            &Ti[w * 16 + l15][kk * 32 + g * 8]);
#pragma unroll
        for (int n = 0; n < 4; ++n) {
            const short8 bb = *reinterpret_cast<const short8*>(
                &Tj[n * 16 + l15][kk * 32 + g * 8]);
            acc[n] = __builtin_amdgcn_mfma_f32_16x16x32_bf16(a, bb, acc[n], 0, 0, 0);
        }
    }

    // epilogue: out = ni[i] + nj[j] - 2*G
    float niv[4];
#pragma unroll
    for (int r = 0; r < 4; ++r) niv[r] = ni[w * 16 + g * 4 + r];
#pragma unroll
    for (int n = 0; n < 4; ++n) {
        const float njv = nj[n * 16 + l15];
#pragma unroll
        for (int r = 0; r < 4; ++r) {
            const int row = i0 + w * 16 + g * 4 + r;
            const int col = j0 + n * 16 + l15;
            out[((size_t)b * S_ + row) * S_ + col] = niv[r] + njv - 2.f * acc[n][r];
        }
    }
}

// ---------------------------------------------------------------------------
extern "C" void kernel_launch(void* const* d_in, const int* in_sizes, int n_in,
                              void* d_out, int out_size, void* d_ws, size_t ws_size,
                              hipStream_t stream) {
    const float* batch = (const float*)d_in[0];   // [8,512,1024] fp32
    const float* proj  = (const float*)d_in[1];   // [1024,128]  fp32
    float* out = (float*)d_out;                   // [8,512,512] fp32

    // ws layout: Pt bf16 [16][128][64] = 256 KB, then T bf16 [4096][128] = 1 MB
    u16* Pt = (u16*)d_ws;
    u16* T  = Pt + 16 * 8192;

    transpose_proj_kernel<<<dim3(16, 4), 256, 0, stream>>>(proj, Pt);
    gemm1_kernel<<<dim3(2, M_ / 16), 256, 0, stream>>>(batch, Pt, T);
    pairdist_kernel<<<dim3(S_ / 64, S_ / 64, B_), 256, 0, stream>>>(T, out);
}